// Round 1
// baseline (314.907 us; speedup 1.0000x reference)
//
#include <hip/hip_runtime.h>
#include <math.h>

#define DIM 1024
#define DEPTH 7
#define PAR 8
#define N_NODES 255   // 2^(DEPTH+1) - 1
#define WIDTH 2040    // PAR * N_NODES

// ---------------------------------------------------------------------------
// Transpose W_out [DIM][WIDTH] -> W_outT [WIDTH][DIM] so stage-2 axpy reads
// contiguous rows. Tiled via LDS, +1 pad to avoid bank conflicts.
// ---------------------------------------------------------------------------
__global__ void transpose_kernel(const float* __restrict__ W_out,
                                 float* __restrict__ W_outT) {
    __shared__ float tile[32][33];
    const int w0 = blockIdx.x * 32;   // WIDTH tile origin
    const int d0 = blockIdx.y * 32;   // DIM tile origin
    const int tx = threadIdx.x;       // 0..31
    const int ty = threadIdx.y;       // 0..7

    #pragma unroll
    for (int i = ty; i < 32; i += 8) {
        int d = d0 + i, w = w0 + tx;
        tile[i][tx] = (w < WIDTH) ? W_out[d * WIDTH + w] : 0.0f;
    }
    __syncthreads();
    #pragma unroll
    for (int i = ty; i < 32; i += 8) {
        int w = w0 + i, d = d0 + tx;
        if (w < WIDTH) W_outT[w * DIM + d] = tile[tx][i];
    }
}

// ---------------------------------------------------------------------------
// One wave (64 lanes) per row. Lane l holds x elements {k*256 + l*4 .. +3}
// for k=0..3 (float4, fully coalesced). For each of 8 trees, walk 8 levels:
// dot(x, W_in[node]) via per-lane FMA + butterfly reduce, silu, fused axpy
// of act * W_outT[node] into per-lane output accumulator.
// ---------------------------------------------------------------------------
template <bool USE_WT>
__global__ __launch_bounds__(256) void fff_kernel(
    const float* __restrict__ x,       // [B, DIM]
    const float* __restrict__ W_in,    // [WIDTH, DIM]
    const float* __restrict__ b_in,    // [WIDTH]
    const float* __restrict__ Wo,      // USE_WT ? W_outT [WIDTH,DIM] : W_out [DIM,WIDTH]
    float* __restrict__ out,           // [B, DIM]
    int B)
{
    const int wave = (int)((blockIdx.x * blockDim.x + threadIdx.x) >> 6);
    const int lane = (int)(threadIdx.x & 63);
    if (wave >= B) return;

    const float* xr = x + (size_t)wave * DIM;
    float4 x4[4];
    #pragma unroll
    for (int k = 0; k < 4; ++k)
        x4[k] = *(const float4*)(xr + k * 256 + lane * 4);

    float4 acc[4];
    #pragma unroll
    for (int k = 0; k < 4; ++k) acc[k] = make_float4(0.f, 0.f, 0.f, 0.f);

    int node[PAR];
    #pragma unroll
    for (int p = 0; p < PAR; ++p) node[p] = 0;

    for (int d = 0; d <= DEPTH; ++d) {
        #pragma unroll
        for (int p = 0; p < PAR; ++p) {
            const int gidx = p * N_NODES + node[p];
            const float* wr = W_in + (size_t)gidx * DIM;

            float4 w4[4];
            #pragma unroll
            for (int k = 0; k < 4; ++k)
                w4[k] = *(const float4*)(wr + k * 256 + lane * 4);

            float partial = 0.f;
            #pragma unroll
            for (int k = 0; k < 4; ++k) {
                partial = fmaf(x4[k].x, w4[k].x, partial);
                partial = fmaf(x4[k].y, w4[k].y, partial);
                partial = fmaf(x4[k].z, w4[k].z, partial);
                partial = fmaf(x4[k].w, w4[k].w, partial);
            }
            // butterfly reduce over the 64-lane wave
            #pragma unroll
            for (int off = 32; off >= 1; off >>= 1)
                partial += __shfl_xor(partial, off, 64);

            const float logit = partial + b_in[gidx];
            const float act   = logit / (1.0f + __expf(-logit));  // silu

            if (USE_WT) {
                const float* wo = Wo + (size_t)gidx * DIM;
                #pragma unroll
                for (int k = 0; k < 4; ++k) {
                    float4 t = *(const float4*)(wo + k * 256 + lane * 4);
                    acc[k].x = fmaf(act, t.x, acc[k].x);
                    acc[k].y = fmaf(act, t.y, acc[k].y);
                    acc[k].z = fmaf(act, t.z, acc[k].z);
                    acc[k].w = fmaf(act, t.w, acc[k].w);
                }
            } else {
                // slow-but-correct fallback: column access of W_out [DIM,WIDTH]
                #pragma unroll
                for (int k = 0; k < 4; ++k) {
                    const int bd = k * 256 + lane * 4;
                    acc[k].x = fmaf(act, Wo[(size_t)(bd + 0) * WIDTH + gidx], acc[k].x);
                    acc[k].y = fmaf(act, Wo[(size_t)(bd + 1) * WIDTH + gidx], acc[k].y);
                    acc[k].z = fmaf(act, Wo[(size_t)(bd + 2) * WIDTH + gidx], acc[k].z);
                    acc[k].w = fmaf(act, Wo[(size_t)(bd + 3) * WIDTH + gidx], acc[k].w);
                }
            }

            const int move = (logit > 0.0f) ? 1 : 0;
            node[p] = 2 * node[p] + 1 + move;   // heap-index descent
        }
    }

    float* orow = out + (size_t)wave * DIM;
    #pragma unroll
    for (int k = 0; k < 4; ++k)
        *(float4*)(orow + k * 256 + lane * 4) = acc[k];
}

extern "C" void kernel_launch(void* const* d_in, const int* in_sizes, int n_in,
                              void* d_out, int out_size, void* d_ws, size_t ws_size,
                              hipStream_t stream) {
    const float* oldx  = (const float*)d_in[0];
    const float* W_in  = (const float*)d_in[1];
    const float* b_in  = (const float*)d_in[2];
    const float* W_out = (const float*)d_in[3];
    float* out = (float*)d_out;

    const int B = in_sizes[0] / DIM;   // 4*2048 = 8192 rows

    const size_t wt_bytes = (size_t)WIDTH * DIM * sizeof(float);
    const bool use_wt = (ws_size >= wt_bytes) && (d_ws != nullptr);

    const int waves_per_block = 4;      // 256 threads
    const int blocks = (B + waves_per_block - 1) / waves_per_block;

    if (use_wt) {
        float* WT = (float*)d_ws;
        dim3 tb(32, 8);
        dim3 tg((WIDTH + 31) / 32, DIM / 32);
        transpose_kernel<<<tg, tb, 0, stream>>>(W_out, WT);
        fff_kernel<true><<<blocks, 256, 0, stream>>>(oldx, W_in, b_in, WT, out, B);
    } else {
        fff_kernel<false><<<blocks, 256, 0, stream>>>(oldx, W_in, b_in, W_out, out, B);
    }
}

// Round 2
// 285.425 us; speedup vs baseline: 1.1033x; 1.1033x over previous
//
#include <hip/hip_runtime.h>
#include <math.h>

#define DIM 1024
#define DEPTH 7
#define PAR 8
#define N_NODES 255   // 2^(DEPTH+1) - 1
#define WIDTH 2040    // PAR * N_NODES

__device__ __forceinline__ unsigned short f32_to_bf16(float f) {
    unsigned int u = __float_as_uint(f);
    u += 0x7fffu + ((u >> 16) & 1u);   // RTNE
    return (unsigned short)(u >> 16);
}

// ---------------------------------------------------------------------------
// Transpose + convert: W_out f32 [DIM][WIDTH] -> WoT bf16 [WIDTH][DIM].
// 64x64 tiles via LDS (pad 65 -> conflict-free), float4 reads, uint2 (4xbf16)
// writes.
// ---------------------------------------------------------------------------
__global__ __launch_bounds__(256) void transpose_bf16_kernel(
    const float* __restrict__ W_out, unsigned short* __restrict__ WoT)
{
    __shared__ float tile[64][65];
    const int w0 = blockIdx.x * 64;
    const int d0 = blockIdx.y * 64;
    const int tid = (int)threadIdx.x;
    const int sub = tid & 15;    // 0..15
    const int grp = tid >> 4;    // 0..15

    #pragma unroll
    for (int pass = 0; pass < 4; ++pass) {
        const int dl = pass * 16 + grp;
        const int wl = sub * 4;
        const int w = w0 + wl;
        const int d = d0 + dl;
        float4 v = make_float4(0.f, 0.f, 0.f, 0.f);
        if (w + 3 < WIDTH) {
            v = *(const float4*)(W_out + (size_t)d * WIDTH + w);
        } else {
            float t0 = (w + 0 < WIDTH) ? W_out[(size_t)d * WIDTH + w + 0] : 0.f;
            float t1 = (w + 1 < WIDTH) ? W_out[(size_t)d * WIDTH + w + 1] : 0.f;
            float t2 = (w + 2 < WIDTH) ? W_out[(size_t)d * WIDTH + w + 2] : 0.f;
            float t3 = (w + 3 < WIDTH) ? W_out[(size_t)d * WIDTH + w + 3] : 0.f;
            v = make_float4(t0, t1, t2, t3);
        }
        tile[dl][wl + 0] = v.x; tile[dl][wl + 1] = v.y;
        tile[dl][wl + 2] = v.z; tile[dl][wl + 3] = v.w;
    }
    __syncthreads();
    #pragma unroll
    for (int pass = 0; pass < 4; ++pass) {
        const int wl = pass * 16 + grp;
        const int dl = sub * 4;
        const int w = w0 + wl;
        if (w < WIDTH) {
            unsigned int b0 = f32_to_bf16(tile[dl + 0][wl]);
            unsigned int b1 = f32_to_bf16(tile[dl + 1][wl]);
            unsigned int b2 = f32_to_bf16(tile[dl + 2][wl]);
            unsigned int b3 = f32_to_bf16(tile[dl + 3][wl]);
            uint2 pk;
            pk.x = b0 | (b1 << 16);
            pk.y = b2 | (b3 << 16);
            *(uint2*)(WoT + (size_t)w * DIM + d0 + dl) = pk;
        }
    }
}

// ---------------------------------------------------------------------------
// One wave per row. Element mapping per lane: e(k,j) = k*512 + lane*8 + j,
// k in {0,1}, j in 0..7 (8 consecutive floats per chunk -> bf16 rows load as
// one dwordx4). Per level: batch all 8 tree dots (max MLP), shared 6-step
// butterfly (8 independent adds per step), then batched silu/axpy/descend.
// ---------------------------------------------------------------------------
template <bool USE_WT>
__global__ __launch_bounds__(256) void fff_kernel(
    const float* __restrict__ x,       // [B, DIM]
    const float* __restrict__ W_in,    // [WIDTH, DIM] f32
    const float* __restrict__ b_in,    // [WIDTH]
    const void*  __restrict__ Wo,      // USE_WT ? bf16 WoT [WIDTH][DIM] : f32 W_out [DIM][WIDTH]
    float* __restrict__ out,           // [B, DIM]
    int B)
{
    const int wave = (int)((blockIdx.x * blockDim.x + threadIdx.x) >> 6);
    const int lane = (int)(threadIdx.x & 63);
    if (wave >= B) return;

    const float* xr = x + (size_t)wave * DIM;
    float4 x4[4];
    #pragma unroll
    for (int k = 0; k < 2; ++k) {
        x4[2 * k + 0] = *(const float4*)(xr + k * 512 + lane * 8 + 0);
        x4[2 * k + 1] = *(const float4*)(xr + k * 512 + lane * 8 + 4);
    }

    float acc[16];
    #pragma unroll
    for (int i = 0; i < 16; ++i) acc[i] = 0.f;

    int node[PAR];
    #pragma unroll
    for (int p = 0; p < PAR; ++p) node[p] = 0;

    for (int d = 0; d <= DEPTH; ++d) {
        int gidx[PAR];
        float partial[PAR];

        // Phase A: all 8 dot-product partials (loads batched for MLP)
        #pragma unroll
        for (int p = 0; p < PAR; ++p) {
            gidx[p] = p * N_NODES + node[p];
            const float* wr = W_in + (size_t)gidx[p] * DIM;
            float s = 0.f;
            #pragma unroll
            for (int k = 0; k < 2; ++k) {
                float4 wa = *(const float4*)(wr + k * 512 + lane * 8 + 0);
                float4 wb = *(const float4*)(wr + k * 512 + lane * 8 + 4);
                s = fmaf(x4[2 * k + 0].x, wa.x, s);
                s = fmaf(x4[2 * k + 0].y, wa.y, s);
                s = fmaf(x4[2 * k + 0].z, wa.z, s);
                s = fmaf(x4[2 * k + 0].w, wa.w, s);
                s = fmaf(x4[2 * k + 1].x, wb.x, s);
                s = fmaf(x4[2 * k + 1].y, wb.y, s);
                s = fmaf(x4[2 * k + 1].z, wb.z, s);
                s = fmaf(x4[2 * k + 1].w, wb.w, s);
            }
            partial[p] = s;
        }

        // Phase B: shared butterfly — 6 dependent steps total, 8 independent
        // adds per step (latency amortized across trees)
        #pragma unroll
        for (int off = 32; off >= 1; off >>= 1) {
            #pragma unroll
            for (int p = 0; p < PAR; ++p)
                partial[p] += __shfl_xor(partial[p], off, 64);
        }

        // Phase C: silu, axpy, descend
        #pragma unroll
        for (int p = 0; p < PAR; ++p) {
            const float logit = partial[p] + b_in[gidx[p]];
            const float act   = logit / (1.0f + __expf(-logit));

            if (USE_WT) {
                const unsigned short* wo =
                    (const unsigned short*)Wo + (size_t)gidx[p] * DIM;
                #pragma unroll
                for (int k = 0; k < 2; ++k) {
                    uint4 u = *(const uint4*)(wo + k * 512 + lane * 8);
                    float f0 = __uint_as_float(u.x << 16);
                    float f1 = __uint_as_float(u.x & 0xffff0000u);
                    float f2 = __uint_as_float(u.y << 16);
                    float f3 = __uint_as_float(u.y & 0xffff0000u);
                    float f4 = __uint_as_float(u.z << 16);
                    float f5 = __uint_as_float(u.z & 0xffff0000u);
                    float f6 = __uint_as_float(u.w << 16);
                    float f7 = __uint_as_float(u.w & 0xffff0000u);
                    acc[k * 8 + 0] = fmaf(act, f0, acc[k * 8 + 0]);
                    acc[k * 8 + 1] = fmaf(act, f1, acc[k * 8 + 1]);
                    acc[k * 8 + 2] = fmaf(act, f2, acc[k * 8 + 2]);
                    acc[k * 8 + 3] = fmaf(act, f3, acc[k * 8 + 3]);
                    acc[k * 8 + 4] = fmaf(act, f4, acc[k * 8 + 4]);
                    acc[k * 8 + 5] = fmaf(act, f5, acc[k * 8 + 5]);
                    acc[k * 8 + 6] = fmaf(act, f6, acc[k * 8 + 6]);
                    acc[k * 8 + 7] = fmaf(act, f7, acc[k * 8 + 7]);
                }
            } else {
                const float* W = (const float*)Wo;
                #pragma unroll
                for (int k = 0; k < 2; ++k) {
                    #pragma unroll
                    for (int j = 0; j < 8; ++j) {
                        const int e = k * 512 + lane * 8 + j;
                        acc[k * 8 + j] =
                            fmaf(act, W[(size_t)e * WIDTH + gidx[p]], acc[k * 8 + j]);
                    }
                }
            }

            node[p] = 2 * node[p] + 1 + ((logit > 0.0f) ? 1 : 0);
        }
    }

    float* orow = out + (size_t)wave * DIM;
    #pragma unroll
    for (int k = 0; k < 2; ++k) {
        float4 lo = make_float4(acc[k * 8 + 0], acc[k * 8 + 1],
                                acc[k * 8 + 2], acc[k * 8 + 3]);
        float4 hi = make_float4(acc[k * 8 + 4], acc[k * 8 + 5],
                                acc[k * 8 + 6], acc[k * 8 + 7]);
        *(float4*)(orow + k * 512 + lane * 8 + 0) = lo;
        *(float4*)(orow + k * 512 + lane * 8 + 4) = hi;
    }
}

extern "C" void kernel_launch(void* const* d_in, const int* in_sizes, int n_in,
                              void* d_out, int out_size, void* d_ws, size_t ws_size,
                              hipStream_t stream) {
    const float* oldx  = (const float*)d_in[0];
    const float* W_in  = (const float*)d_in[1];
    const float* b_in  = (const float*)d_in[2];
    const float* W_out = (const float*)d_in[3];
    float* out = (float*)d_out;

    const int B = in_sizes[0] / DIM;   // 8192 rows

    const size_t wt_bytes = (size_t)WIDTH * DIM * sizeof(unsigned short);
    const bool use_wt = (ws_size >= wt_bytes) && (d_ws != nullptr);

    const int waves_per_block = 4;      // 256 threads
    const int blocks = (B + waves_per_block - 1) / waves_per_block;

    if (use_wt) {
        unsigned short* WT = (unsigned short*)d_ws;
        dim3 tg((WIDTH + 63) / 64, DIM / 64);
        transpose_bf16_kernel<<<tg, 256, 0, stream>>>(W_out, WT);
        fff_kernel<true><<<blocks, 256, 0, stream>>>(oldx, W_in, b_in, WT, out, B);
    } else {
        fff_kernel<false><<<blocks, 256, 0, stream>>>(oldx, W_in, b_in, W_out, out, B);
    }
}

// Round 3
// 194.289 us; speedup vs baseline: 1.6208x; 1.4691x over previous
//
#include <hip/hip_runtime.h>
#include <math.h>

#define DIM 1024
#define DEPTH 7
#define PAR 8
#define N_NODES 255   // 2^(DEPTH+1) - 1
#define WIDTH 2040    // PAR * N_NODES
#define MARGIN 0.02f  // |logit| below this -> recompute dot in fp32 (decision safety)

__device__ __forceinline__ unsigned short f32_to_bf16(float f) {
    unsigned int u = __float_as_uint(f);
    u += 0x7fffu + ((u >> 16) & 1u);   // RTNE
    return (unsigned short)(u >> 16);
}
__device__ __forceinline__ float bf_lo(unsigned int u) { return __uint_as_float(u << 16); }
__device__ __forceinline__ float bf_hi(unsigned int u) { return __uint_as_float(u & 0xffff0000u); }

// fma two bf16 (packed in dword u) against a0,a1
__device__ __forceinline__ float fma2(float a0, float a1, unsigned int u, float s) {
    s = fmaf(a0, bf_lo(u), s);
    return fmaf(a1, bf_hi(u), s);
}

// ---------------------------------------------------------------------------
// Elementwise convert W_in f32 -> bf16 (same [WIDTH][DIM] layout)
// ---------------------------------------------------------------------------
__global__ __launch_bounds__(256) void convert_bf16_kernel(
    const float* __restrict__ src, unsigned short* __restrict__ dst, int n4)
{
    int i = (int)(blockIdx.x * blockDim.x + threadIdx.x);
    if (i < n4) {
        float4 v = ((const float4*)src)[i];
        uint2 pk;
        pk.x = (unsigned)f32_to_bf16(v.x) | ((unsigned)f32_to_bf16(v.y) << 16);
        pk.y = (unsigned)f32_to_bf16(v.z) | ((unsigned)f32_to_bf16(v.w) << 16);
        ((uint2*)dst)[i] = pk;
    }
}

// ---------------------------------------------------------------------------
// Transpose + convert: W_out f32 [DIM][WIDTH] -> WoT bf16 [WIDTH][DIM]
// ---------------------------------------------------------------------------
__global__ __launch_bounds__(256) void transpose_bf16_kernel(
    const float* __restrict__ W_out, unsigned short* __restrict__ WoT)
{
    __shared__ float tile[64][65];
    const int w0 = blockIdx.x * 64;
    const int d0 = blockIdx.y * 64;
    const int tid = (int)threadIdx.x;
    const int sub = tid & 15;
    const int grp = tid >> 4;

    #pragma unroll
    for (int pass = 0; pass < 4; ++pass) {
        const int dl = pass * 16 + grp;
        const int wl = sub * 4;
        const int w = w0 + wl;
        const int d = d0 + dl;
        float4 v = make_float4(0.f, 0.f, 0.f, 0.f);
        if (w + 3 < WIDTH) {
            v = *(const float4*)(W_out + (size_t)d * WIDTH + w);
        } else {
            float t0 = (w + 0 < WIDTH) ? W_out[(size_t)d * WIDTH + w + 0] : 0.f;
            float t1 = (w + 1 < WIDTH) ? W_out[(size_t)d * WIDTH + w + 1] : 0.f;
            float t2 = (w + 2 < WIDTH) ? W_out[(size_t)d * WIDTH + w + 2] : 0.f;
            float t3 = (w + 3 < WIDTH) ? W_out[(size_t)d * WIDTH + w + 3] : 0.f;
            v = make_float4(t0, t1, t2, t3);
        }
        tile[dl][wl + 0] = v.x; tile[dl][wl + 1] = v.y;
        tile[dl][wl + 2] = v.z; tile[dl][wl + 3] = v.w;
    }
    __syncthreads();
    #pragma unroll
    for (int pass = 0; pass < 4; ++pass) {
        const int wl = pass * 16 + grp;
        const int dl = sub * 4;
        const int w = w0 + wl;
        if (w < WIDTH) {
            unsigned int b0 = f32_to_bf16(tile[dl + 0][wl]);
            unsigned int b1 = f32_to_bf16(tile[dl + 1][wl]);
            unsigned int b2 = f32_to_bf16(tile[dl + 2][wl]);
            unsigned int b3 = f32_to_bf16(tile[dl + 3][wl]);
            uint2 pk;
            pk.x = b0 | (b1 << 16);
            pk.y = b2 | (b3 << 16);
            *(uint2*)(WoT + (size_t)w * DIM + d0 + dl) = pk;
        }
    }
}

// ---------------------------------------------------------------------------
// Main kernel: one wave per row; bf16 gathers for both stages; fp32 repair of
// near-zero logits (wave-uniform ballot loop). Tree nodes packed in one u64.
// d-loop NOT unrolled (I-cache: body ~5.6 KB instead of ~45 KB).
// ---------------------------------------------------------------------------
__global__ __launch_bounds__(256) void fff_bf16_kernel(
    const float* __restrict__ x,          // [B, DIM] f32
    const float* __restrict__ W_in,       // [WIDTH, DIM] f32 (repair only)
    const float* __restrict__ b_in,       // [WIDTH] f32
    const unsigned short* __restrict__ Wb,  // bf16 W_in  [WIDTH][DIM]
    const unsigned short* __restrict__ WoT, // bf16 W_out^T [WIDTH][DIM]
    float* __restrict__ out,              // [B, DIM] f32
    int B)
{
    const int wave = (int)((blockIdx.x * blockDim.x + threadIdx.x) >> 6);
    const int lane = (int)(threadIdx.x & 63);
    if (wave >= B) return;

    const float* xr = x + (size_t)wave * DIM;
    float4 x4[4];
    x4[0] = *(const float4*)(xr + lane * 8 + 0);
    x4[1] = *(const float4*)(xr + lane * 8 + 4);
    x4[2] = *(const float4*)(xr + 512 + lane * 8 + 0);
    x4[3] = *(const float4*)(xr + 512 + lane * 8 + 4);

    float acc[16];
    #pragma unroll
    for (int i = 0; i < 16; ++i) acc[i] = 0.f;

    unsigned long long nodes = 0ULL;   // 8 x u8 node indices (all < 255)

    #pragma unroll 1
    for (int d = 0; d <= DEPTH; ++d) {
        int gidx[PAR];
        float partial[PAR];

        // Phase A: bf16 dot partials for all 8 trees (batched loads -> MLP)
        #pragma unroll
        for (int p = 0; p < PAR; ++p) {
            const int np = (int)((nodes >> (8 * p)) & 0xffULL);
            gidx[p] = p * N_NODES + np;
            const unsigned short* wr = Wb + (size_t)gidx[p] * DIM;
            const uint4 u0 = *(const uint4*)(wr + lane * 8);
            const uint4 u1 = *(const uint4*)(wr + 512 + lane * 8);
            float s = 0.f;
            s = fma2(x4[0].x, x4[0].y, u0.x, s);
            s = fma2(x4[0].z, x4[0].w, u0.y, s);
            s = fma2(x4[1].x, x4[1].y, u0.z, s);
            s = fma2(x4[1].z, x4[1].w, u0.w, s);
            s = fma2(x4[2].x, x4[2].y, u1.x, s);
            s = fma2(x4[2].z, x4[2].w, u1.y, s);
            s = fma2(x4[3].x, x4[3].y, u1.z, s);
            s = fma2(x4[3].z, x4[3].w, u1.w, s);
            partial[p] = s;
        }

        // Phase B: shared butterfly (6 dependent steps, 8 independent adds each)
        #pragma unroll
        for (int off = 32; off >= 1; off >>= 1) {
            #pragma unroll
            for (int p = 0; p < PAR; ++p)
                partial[p] += __shfl_xor(partial[p], off, 64);
        }

        // lane p (p<8) holds tree p's logit in `my`
        float my = partial[0] + b_in[gidx[0]];
        #pragma unroll
        for (int p = 1; p < PAR; ++p) {
            const float lp = partial[p] + b_in[gidx[p]];
            my = (lane == p) ? lp : my;
        }

        // Repair: near-zero logits recomputed in fp32 (decisions must match numpy)
        if (d < DEPTH) {
            unsigned long long bal = __ballot(lane < PAR && fabsf(my) < MARGIN);
            unsigned m = (unsigned)(bal & 0xffULL);
            while (m) {
                const int p = __builtin_ctz(m); m &= (m - 1u);
                const int np = (int)((nodes >> (8 * p)) & 0xffULL);
                const int gi = p * N_NODES + np;
                const float* wr = W_in + (size_t)gi * DIM;
                const float4 wa = *(const float4*)(wr + lane * 8 + 0);
                const float4 wb = *(const float4*)(wr + lane * 8 + 4);
                const float4 wc = *(const float4*)(wr + 512 + lane * 8 + 0);
                const float4 wd = *(const float4*)(wr + 512 + lane * 8 + 4);
                float s = 0.f;
                s = fmaf(x4[0].x, wa.x, s); s = fmaf(x4[0].y, wa.y, s);
                s = fmaf(x4[0].z, wa.z, s); s = fmaf(x4[0].w, wa.w, s);
                s = fmaf(x4[1].x, wb.x, s); s = fmaf(x4[1].y, wb.y, s);
                s = fmaf(x4[1].z, wb.z, s); s = fmaf(x4[1].w, wb.w, s);
                s = fmaf(x4[2].x, wc.x, s); s = fmaf(x4[2].y, wc.y, s);
                s = fmaf(x4[2].z, wc.z, s); s = fmaf(x4[2].w, wc.w, s);
                s = fmaf(x4[3].x, wd.x, s); s = fmaf(x4[3].y, wd.y, s);
                s = fmaf(x4[3].z, wd.z, s); s = fmaf(x4[3].w, wd.w, s);
                #pragma unroll
                for (int off = 32; off >= 1; off >>= 1)
                    s += __shfl_xor(s, off, 64);
                const float lf = s + b_in[gi];
                my = (lane == p) ? lf : my;
            }
        }

        // Phase C: broadcast logit, silu, bf16 axpy, descend
        #pragma unroll
        for (int p = 0; p < PAR; ++p) {
            const float lg = __shfl(my, p, 64);
            const float act = lg / (1.0f + __expf(-lg));

            const unsigned short* wo = WoT + (size_t)gidx[p] * DIM;
            const uint4 u0 = *(const uint4*)(wo + lane * 8);
            const uint4 u1 = *(const uint4*)(wo + 512 + lane * 8);
            acc[0]  = fmaf(act, bf_lo(u0.x), acc[0]);
            acc[1]  = fmaf(act, bf_hi(u0.x), acc[1]);
            acc[2]  = fmaf(act, bf_lo(u0.y), acc[2]);
            acc[3]  = fmaf(act, bf_hi(u0.y), acc[3]);
            acc[4]  = fmaf(act, bf_lo(u0.z), acc[4]);
            acc[5]  = fmaf(act, bf_hi(u0.z), acc[5]);
            acc[6]  = fmaf(act, bf_lo(u0.w), acc[6]);
            acc[7]  = fmaf(act, bf_hi(u0.w), acc[7]);
            acc[8]  = fmaf(act, bf_lo(u1.x), acc[8]);
            acc[9]  = fmaf(act, bf_hi(u1.x), acc[9]);
            acc[10] = fmaf(act, bf_lo(u1.y), acc[10]);
            acc[11] = fmaf(act, bf_hi(u1.y), acc[11]);
            acc[12] = fmaf(act, bf_lo(u1.z), acc[12]);
            acc[13] = fmaf(act, bf_hi(u1.z), acc[13]);
            acc[14] = fmaf(act, bf_lo(u1.w), acc[14]);
            acc[15] = fmaf(act, bf_hi(u1.w), acc[15]);

            if (d < DEPTH) {
                const int np = (int)((nodes >> (8 * p)) & 0xffULL);
                const unsigned long long nn =
                    (unsigned long long)(2 * np + 1 + ((lg > 0.0f) ? 1 : 0));
                nodes = (nodes & ~(0xffULL << (8 * p))) | (nn << (8 * p));
            }
        }
    }

    float* orow = out + (size_t)wave * DIM;
    *(float4*)(orow + lane * 8 + 0)       = make_float4(acc[0],  acc[1],  acc[2],  acc[3]);
    *(float4*)(orow + lane * 8 + 4)       = make_float4(acc[4],  acc[5],  acc[6],  acc[7]);
    *(float4*)(orow + 512 + lane * 8 + 0) = make_float4(acc[8],  acc[9],  acc[10], acc[11]);
    *(float4*)(orow + 512 + lane * 8 + 4) = make_float4(acc[12], acc[13], acc[14], acc[15]);
}

// ---------------------------------------------------------------------------
// Fallback (no workspace): fp32 gather both stages, W_out accessed by column.
// Correct but slow; only used if ws_size is unexpectedly tiny.
// ---------------------------------------------------------------------------
__global__ __launch_bounds__(256) void fff_fallback_kernel(
    const float* __restrict__ x, const float* __restrict__ W_in,
    const float* __restrict__ b_in, const float* __restrict__ W_out,
    float* __restrict__ out, int B)
{
    const int wave = (int)((blockIdx.x * blockDim.x + threadIdx.x) >> 6);
    const int lane = (int)(threadIdx.x & 63);
    if (wave >= B) return;

    const float* xr = x + (size_t)wave * DIM;
    float4 x4[4];
    x4[0] = *(const float4*)(xr + lane * 8 + 0);
    x4[1] = *(const float4*)(xr + lane * 8 + 4);
    x4[2] = *(const float4*)(xr + 512 + lane * 8 + 0);
    x4[3] = *(const float4*)(xr + 512 + lane * 8 + 4);

    float acc[16];
    #pragma unroll
    for (int i = 0; i < 16; ++i) acc[i] = 0.f;
    int node[PAR];
    #pragma unroll
    for (int p = 0; p < PAR; ++p) node[p] = 0;

    for (int d = 0; d <= DEPTH; ++d) {
        #pragma unroll
        for (int p = 0; p < PAR; ++p) {
            const int gidx = p * N_NODES + node[p];
            const float* wr = W_in + (size_t)gidx * DIM;
            const float4 wa = *(const float4*)(wr + lane * 8 + 0);
            const float4 wb = *(const float4*)(wr + lane * 8 + 4);
            const float4 wc = *(const float4*)(wr + 512 + lane * 8 + 0);
            const float4 wd = *(const float4*)(wr + 512 + lane * 8 + 4);
            float s = 0.f;
            s = fmaf(x4[0].x, wa.x, s); s = fmaf(x4[0].y, wa.y, s);
            s = fmaf(x4[0].z, wa.z, s); s = fmaf(x4[0].w, wa.w, s);
            s = fmaf(x4[1].x, wb.x, s); s = fmaf(x4[1].y, wb.y, s);
            s = fmaf(x4[1].z, wb.z, s); s = fmaf(x4[1].w, wb.w, s);
            s = fmaf(x4[2].x, wc.x, s); s = fmaf(x4[2].y, wc.y, s);
            s = fmaf(x4[2].z, wc.z, s); s = fmaf(x4[2].w, wc.w, s);
            s = fmaf(x4[3].x, wd.x, s); s = fmaf(x4[3].y, wd.y, s);
            s = fmaf(x4[3].z, wd.z, s); s = fmaf(x4[3].w, wd.w, s);
            #pragma unroll
            for (int off = 32; off >= 1; off >>= 1)
                s += __shfl_xor(s, off, 64);
            const float logit = s + b_in[gidx];
            const float act = logit / (1.0f + __expf(-logit));
            #pragma unroll
            for (int k = 0; k < 2; ++k) {
                #pragma unroll
                for (int j = 0; j < 8; ++j) {
                    const int e = k * 512 + lane * 8 + j;
                    acc[k * 8 + j] = fmaf(act, W_out[(size_t)e * WIDTH + gidx], acc[k * 8 + j]);
                }
            }
            node[p] = 2 * node[p] + 1 + ((logit > 0.0f) ? 1 : 0);
        }
    }

    float* orow = out + (size_t)wave * DIM;
    *(float4*)(orow + lane * 8 + 0)       = make_float4(acc[0],  acc[1],  acc[2],  acc[3]);
    *(float4*)(orow + lane * 8 + 4)       = make_float4(acc[4],  acc[5],  acc[6],  acc[7]);
    *(float4*)(orow + 512 + lane * 8 + 0) = make_float4(acc[8],  acc[9],  acc[10], acc[11]);
    *(float4*)(orow + 512 + lane * 8 + 4) = make_float4(acc[12], acc[13], acc[14], acc[15]);
}

extern "C" void kernel_launch(void* const* d_in, const int* in_sizes, int n_in,
                              void* d_out, int out_size, void* d_ws, size_t ws_size,
                              hipStream_t stream) {
    const float* oldx  = (const float*)d_in[0];
    const float* W_in  = (const float*)d_in[1];
    const float* b_in  = (const float*)d_in[2];
    const float* W_out = (const float*)d_in[3];
    float* out = (float*)d_out;

    const int B = in_sizes[0] / DIM;   // 8192 rows

    const size_t half = (size_t)WIDTH * DIM * sizeof(unsigned short);  // 4.18 MB
    const bool use_bf16 = (ws_size >= 2 * half) && (d_ws != nullptr);

    const int blocks = (B + 3) / 4;    // 4 waves (256 threads) per block

    if (use_bf16) {
        unsigned short* WoT = (unsigned short*)d_ws;
        unsigned short* Wb  = (unsigned short*)((char*)d_ws + half);
        dim3 tg((WIDTH + 63) / 64, DIM / 64);
        transpose_bf16_kernel<<<tg, 256, 0, stream>>>(W_out, WoT);
        const int n4 = WIDTH * DIM / 4;
        convert_bf16_kernel<<<(n4 + 255) / 256, 256, 0, stream>>>(W_in, (unsigned short*)Wb, n4);
        fff_bf16_kernel<<<blocks, 256, 0, stream>>>(oldx, W_in, b_in, Wb, WoT, out, B);
    } else {
        fff_fallback_kernel<<<blocks, 256, 0, stream>>>(oldx, W_in, b_in, W_out, out, B);
    }
}

// Round 5
// 187.805 us; speedup vs baseline: 1.6768x; 1.0345x over previous
//
#include <hip/hip_runtime.h>
#include <math.h>

#define DIM 1024
#define DEPTH 7
#define PAR 8
#define N_NODES 255   // 2^(DEPTH+1) - 1
#define WIDTH 2040    // PAR * N_NODES
#define MARGIN 0.03f  // |logit| below this -> recompute dot in fp32 (decision safety)

// lane that holds tree p's reduced logit after the fold network (bits 8/16/32)
#define REPLANE(p) ((((p) & 1) << 3) | ((((p) >> 1) & 1) << 4) | ((((p) >> 2) & 1) << 5))

typedef float  float2v  __attribute__((ext_vector_type(2)));
typedef _Float16 half2v __attribute__((ext_vector_type(2)));

__device__ __forceinline__ unsigned short f32_to_bf16(float f) {
    unsigned int u = __float_as_uint(f);
    u += 0x7fffu + ((u >> 16) & 1u);   // RTNE
    return (unsigned short)(u >> 16);
}
__device__ __forceinline__ float bf_lo(unsigned int u) { return __uint_as_float(u << 16); }
__device__ __forceinline__ float bf_hi(unsigned int u) { return __uint_as_float(u & 0xffff0000u); }

__device__ __forceinline__ half2v as_h2(unsigned int u) {
    union { unsigned int u; half2v h; } c; c.u = u; return c.h;
}
__device__ __forceinline__ unsigned int pack_h2(float a, float b) {
    union { half2v h; unsigned int u; } c;
    c.h = (half2v){(_Float16)a, (_Float16)b};   // v_cvt_f16_f32 is RTNE
    return c.u;
}

// f16 dot2 with fp32 accumulate; builtin if available, exact fallback otherwise
__device__ __forceinline__ float dot2h(unsigned int a, unsigned int b, float c) {
#if __has_builtin(__builtin_amdgcn_fdot2)
    return __builtin_amdgcn_fdot2(as_h2(a), as_h2(b), c, false);
#else
    half2v ha = as_h2(a), hb = as_h2(b);
    c = fmaf((float)ha.x, (float)hb.x, c);
    return fmaf((float)ha.y, (float)hb.y, c);
#endif
}

// fold two per-lane partial sums into one register, separating them by lane bit K.
__device__ __forceinline__ float foldK(float a, float b, int K) {
    const bool hi = (threadIdx.x & (unsigned)K) != 0;
    const float keep = hi ? b : a;
    const float send = hi ? a : b;
    return keep + __shfl_xor(send, K, 64);
}

// ---------------------------------------------------------------------------
// W_in f32 -> f16 packed (same [WIDTH][DIM] layout)
// ---------------------------------------------------------------------------
__global__ __launch_bounds__(256) void convert_f16_kernel(
    const float* __restrict__ src, unsigned int* __restrict__ dst, int n4)
{
    int i = (int)(blockIdx.x * blockDim.x + threadIdx.x);
    if (i < n4) {
        float4 v = ((const float4*)src)[i];
        uint2 pk;
        pk.x = pack_h2(v.x, v.y);
        pk.y = pack_h2(v.z, v.w);
        ((uint2*)dst)[i] = pk;
    }
}

// ---------------------------------------------------------------------------
// Transpose + convert: W_out f32 [DIM][WIDTH] -> WoT bf16 [WIDTH][DIM]
// (identical to the round-3 verified version)
// ---------------------------------------------------------------------------
__global__ __launch_bounds__(256) void transpose_bf16_kernel(
    const float* __restrict__ W_out, unsigned short* __restrict__ WoT)
{
    __shared__ float tile[64][65];
    const int w0 = blockIdx.x * 64;
    const int d0 = blockIdx.y * 64;
    const int tid = (int)threadIdx.x;
    const int sub = tid & 15;
    const int grp = tid >> 4;

    #pragma unroll
    for (int pass = 0; pass < 4; ++pass) {
        const int dl = pass * 16 + grp;
        const int wl = sub * 4;
        const int w = w0 + wl;
        const int d = d0 + dl;
        float4 v = make_float4(0.f, 0.f, 0.f, 0.f);
        if (w + 3 < WIDTH) {
            v = *(const float4*)(W_out + (size_t)d * WIDTH + w);
        } else {
            float t0 = (w + 0 < WIDTH) ? W_out[(size_t)d * WIDTH + w + 0] : 0.f;
            float t1 = (w + 1 < WIDTH) ? W_out[(size_t)d * WIDTH + w + 1] : 0.f;
            float t2 = (w + 2 < WIDTH) ? W_out[(size_t)d * WIDTH + w + 2] : 0.f;
            float t3 = (w + 3 < WIDTH) ? W_out[(size_t)d * WIDTH + w + 3] : 0.f;
            v = make_float4(t0, t1, t2, t3);
        }
        tile[dl][wl + 0] = v.x; tile[dl][wl + 1] = v.y;
        tile[dl][wl + 2] = v.z; tile[dl][wl + 3] = v.w;
    }
    __syncthreads();
    #pragma unroll
    for (int pass = 0; pass < 4; ++pass) {
        const int wl = pass * 16 + grp;
        const int dl = sub * 4;
        const int w = w0 + wl;
        if (w < WIDTH) {
            unsigned int b0 = f32_to_bf16(tile[dl + 0][wl]);
            unsigned int b1 = f32_to_bf16(tile[dl + 1][wl]);
            unsigned int b2 = f32_to_bf16(tile[dl + 2][wl]);
            unsigned int b3 = f32_to_bf16(tile[dl + 3][wl]);
            uint2 pk;
            pk.x = b0 | (b1 << 16);
            pk.y = b2 | (b3 << 16);
            *(uint2*)(WoT + (size_t)w * DIM + d0 + dl) = pk;
        }
    }
}

// ---------------------------------------------------------------------------
// Main kernel: one wave per row. f16 x (packed) x f16 W via fdot2 builtin,
// fold-network reduction, per-lane silu + one-ballot decisions, float2
// (compiler pk_fma) stage-2 on bf16 WoT, fp32 repair for near-zero logits.
// ---------------------------------------------------------------------------
__global__ __launch_bounds__(256) void fff_f16_kernel(
    const float* __restrict__ x,            // [B, DIM] f32
    const float* __restrict__ W_in,         // [WIDTH, DIM] f32 (repair only)
    const float* __restrict__ b_in,         // [WIDTH] f32
    const unsigned int* __restrict__ Wh,    // f16 W_in  [WIDTH][DIM/2] dwords
    const unsigned short* __restrict__ WoT, // bf16 W_out^T [WIDTH][DIM]
    float* __restrict__ out,                // [B, DIM] f32
    int B)
{
    const int wave = (int)((blockIdx.x * blockDim.x + threadIdx.x) >> 6);
    const int lane = (int)(threadIdx.x & 63);
    if (wave >= B) return;

    const float* xr = x + (size_t)wave * DIM;
    unsigned int xp[8];
    {
        float4 a0 = *(const float4*)(xr + lane * 8 + 0);
        float4 a1 = *(const float4*)(xr + lane * 8 + 4);
        float4 a2 = *(const float4*)(xr + 512 + lane * 8 + 0);
        float4 a3 = *(const float4*)(xr + 512 + lane * 8 + 4);
        xp[0] = pack_h2(a0.x, a0.y);
        xp[1] = pack_h2(a0.z, a0.w);
        xp[2] = pack_h2(a1.x, a1.y);
        xp[3] = pack_h2(a1.z, a1.w);
        xp[4] = pack_h2(a2.x, a2.y);
        xp[5] = pack_h2(a2.z, a2.w);
        xp[6] = pack_h2(a3.x, a3.y);
        xp[7] = pack_h2(a3.z, a3.w);
    }

    float2v acc2[8];
    #pragma unroll
    for (int i = 0; i < 8; ++i) acc2[i] = (float2v){0.f, 0.f};

    unsigned long long nodes = 0ULL;   // 8 x u8 node indices (all < 255)
    const int myp = ((lane >> 3) & 1) | (((lane >> 4) & 1) << 1) | (((lane >> 5) & 1) << 2);

    #pragma unroll 1
    for (int d = 0; d <= DEPTH; ++d) {
        int gidx[PAR];
        float partial[PAR];

        // Phase A: f16 dot partials, one v_dot2_f32_f16 per dword
        #pragma unroll
        for (int p = 0; p < PAR; ++p) {
            const int np = (int)((nodes >> (8 * p)) & 0xffULL);
            gidx[p] = p * N_NODES + np;
            const unsigned int* wr = Wh + (size_t)gidx[p] * (DIM / 2);
            const uint4 u0 = *(const uint4*)(wr + lane * 4);
            const uint4 u1 = *(const uint4*)(wr + 256 + lane * 4);
            float s = 0.f;
            s = dot2h(xp[0], u0.x, s);
            s = dot2h(xp[1], u0.y, s);
            s = dot2h(xp[2], u0.z, s);
            s = dot2h(xp[3], u0.w, s);
            s = dot2h(xp[4], u1.x, s);
            s = dot2h(xp[5], u1.y, s);
            s = dot2h(xp[6], u1.z, s);
            s = dot2h(xp[7], u1.w, s);
            partial[p] = s;
        }

        // Phase B: fold network over lane bits {8,16,32}, butterfly over {1,2,4}
        const float c01 = foldK(partial[0], partial[1], 8);
        const float c23 = foldK(partial[2], partial[3], 8);
        const float c45 = foldK(partial[4], partial[5], 8);
        const float c67 = foldK(partial[6], partial[7], 8);
        const float d0f = foldK(c01, c23, 16);
        const float d1f = foldK(c45, c67, 16);
        float e = foldK(d0f, d1f, 32);
        e += __shfl_xor(e, 1, 64);
        e += __shfl_xor(e, 2, 64);
        e += __shfl_xor(e, 4, 64);

        const int ga = (lane & 8) ? gidx[1] : gidx[0];
        const int gb = (lane & 8) ? gidx[3] : gidx[2];
        const int gc = (lane & 8) ? gidx[5] : gidx[4];
        const int gd = (lane & 8) ? gidx[7] : gidx[6];
        const int ge = (lane & 16) ? gb : ga;
        const int gf = (lane & 16) ? gd : gc;
        const int gmine = (lane & 32) ? gf : ge;
        float my = e + b_in[gmine];

        // Repair: near-zero logits recomputed in fp32 (decisions must match numpy)
        if (d < DEPTH) {
            const unsigned long long bal = __ballot(fabsf(my) < MARGIN);
            unsigned rm = 0;
            #pragma unroll
            for (int p = 0; p < PAR; ++p)
                rm |= ((unsigned)((bal >> REPLANE(p)) & 1ULL)) << p;
            if (rm) {
                const float4 fa = *(const float4*)(xr + lane * 8 + 0);
                const float4 fb = *(const float4*)(xr + lane * 8 + 4);
                const float4 fc = *(const float4*)(xr + 512 + lane * 8 + 0);
                const float4 fd = *(const float4*)(xr + 512 + lane * 8 + 4);
                while (rm) {
                    const int p = __builtin_ctz(rm); rm &= (rm - 1u);
                    const int np = (int)((nodes >> (8 * p)) & 0xffULL);
                    const int gi = p * N_NODES + np;
                    const float* wr = W_in + (size_t)gi * DIM;
                    const float4 wa = *(const float4*)(wr + lane * 8 + 0);
                    const float4 wb = *(const float4*)(wr + lane * 8 + 4);
                    const float4 wc = *(const float4*)(wr + 512 + lane * 8 + 0);
                    const float4 wd = *(const float4*)(wr + 512 + lane * 8 + 4);
                    float s = 0.f;
                    s = fmaf(fa.x, wa.x, s); s = fmaf(fa.y, wa.y, s);
                    s = fmaf(fa.z, wa.z, s); s = fmaf(fa.w, wa.w, s);
                    s = fmaf(fb.x, wb.x, s); s = fmaf(fb.y, wb.y, s);
                    s = fmaf(fb.z, wb.z, s); s = fmaf(fb.w, wb.w, s);
                    s = fmaf(fc.x, wc.x, s); s = fmaf(fc.y, wc.y, s);
                    s = fmaf(fc.z, wc.z, s); s = fmaf(fc.w, wc.w, s);
                    s = fmaf(fd.x, wd.x, s); s = fmaf(fd.y, wd.y, s);
                    s = fmaf(fd.z, wd.z, s); s = fmaf(fd.w, wd.w, s);
                    #pragma unroll
                    for (int off = 32; off >= 1; off >>= 1)
                        s += __shfl_xor(s, off, 64);
                    const float lf = s + b_in[gi];
                    my = (myp == p) ? lf : my;
                }
            }
        }

        // per-lane silu (8 trees in parallel), decisions via one ballot
        const float act_mine = my / (1.0f + __expf(-my));
        const unsigned long long pos = __ballot(my > 0.0f);

        float act[PAR];
        #pragma unroll
        for (int p = 0; p < PAR; ++p)
            act[p] = __shfl(act_mine, REPLANE(p), 64);

        // Phase C: float2 (compiler v_pk_fma_f32) axpy of bf16 WoT rows
        #pragma unroll
        for (int p = 0; p < PAR; ++p) {
            const unsigned short* wo = WoT + (size_t)gidx[p] * DIM;
            const uint4 u0 = *(const uint4*)(wo + lane * 8);
            const uint4 u1 = *(const uint4*)(wo + 512 + lane * 8);
            const float2v a2 = (float2v){act[p], act[p]};
            acc2[0] += a2 * (float2v){bf_lo(u0.x), bf_hi(u0.x)};
            acc2[1] += a2 * (float2v){bf_lo(u0.y), bf_hi(u0.y)};
            acc2[2] += a2 * (float2v){bf_lo(u0.z), bf_hi(u0.z)};
            acc2[3] += a2 * (float2v){bf_lo(u0.w), bf_hi(u0.w)};
            acc2[4] += a2 * (float2v){bf_lo(u1.x), bf_hi(u1.x)};
            acc2[5] += a2 * (float2v){bf_lo(u1.y), bf_hi(u1.y)};
            acc2[6] += a2 * (float2v){bf_lo(u1.z), bf_hi(u1.z)};
            acc2[7] += a2 * (float2v){bf_lo(u1.w), bf_hi(u1.w)};

            if (d < DEPTH) {
                const int np = (int)((nodes >> (8 * p)) & 0xffULL);
                const unsigned long long nn = (unsigned long long)
                    (2 * np + 1 + (int)((pos >> REPLANE(p)) & 1ULL));
                nodes = (nodes & ~(0xffULL << (8 * p))) | (nn << (8 * p));
            }
        }
    }

    float* orow = out + (size_t)wave * DIM;
    *(float4*)(orow + lane * 8 + 0) =
        make_float4(acc2[0].x, acc2[0].y, acc2[1].x, acc2[1].y);
    *(float4*)(orow + lane * 8 + 4) =
        make_float4(acc2[2].x, acc2[2].y, acc2[3].x, acc2[3].y);
    *(float4*)(orow + 512 + lane * 8 + 0) =
        make_float4(acc2[4].x, acc2[4].y, acc2[5].x, acc2[5].y);
    *(float4*)(orow + 512 + lane * 8 + 4) =
        make_float4(acc2[6].x, acc2[6].y, acc2[7].x, acc2[7].y);
}

// ---------------------------------------------------------------------------
// Fallback (no workspace): fp32 gather both stages. Correct but slow.
// ---------------------------------------------------------------------------
__global__ __launch_bounds__(256) void fff_fallback_kernel(
    const float* __restrict__ x, const float* __restrict__ W_in,
    const float* __restrict__ b_in, const float* __restrict__ W_out,
    float* __restrict__ out, int B)
{
    const int wave = (int)((blockIdx.x * blockDim.x + threadIdx.x) >> 6);
    const int lane = (int)(threadIdx.x & 63);
    if (wave >= B) return;

    const float* xr = x + (size_t)wave * DIM;
    float4 x4[4];
    x4[0] = *(const float4*)(xr + lane * 8 + 0);
    x4[1] = *(const float4*)(xr + lane * 8 + 4);
    x4[2] = *(const float4*)(xr + 512 + lane * 8 + 0);
    x4[3] = *(const float4*)(xr + 512 + lane * 8 + 4);

    float acc[16];
    #pragma unroll
    for (int i = 0; i < 16; ++i) acc[i] = 0.f;
    int node[PAR];
    #pragma unroll
    for (int p = 0; p < PAR; ++p) node[p] = 0;

    for (int d = 0; d <= DEPTH; ++d) {
        #pragma unroll
        for (int p = 0; p < PAR; ++p) {
            const int gidx = p * N_NODES + node[p];
            const float* wr = W_in + (size_t)gidx * DIM;
            const float4 wa = *(const float4*)(wr + lane * 8 + 0);
            const float4 wb = *(const float4*)(wr + lane * 8 + 4);
            const float4 wc = *(const float4*)(wr + 512 + lane * 8 + 0);
            const float4 wd = *(const float4*)(wr + 512 + lane * 8 + 4);
            float s = 0.f;
            s = fmaf(x4[0].x, wa.x, s); s = fmaf(x4[0].y, wa.y, s);
            s = fmaf(x4[0].z, wa.z, s); s = fmaf(x4[0].w, wa.w, s);
            s = fmaf(x4[1].x, wb.x, s); s = fmaf(x4[1].y, wb.y, s);
            s = fmaf(x4[1].z, wb.z, s); s = fmaf(x4[1].w, wb.w, s);
            s = fmaf(x4[2].x, wc.x, s); s = fmaf(x4[2].y, wc.y, s);
            s = fmaf(x4[2].z, wc.z, s); s = fmaf(x4[2].w, wc.w, s);
            s = fmaf(x4[3].x, wd.x, s); s = fmaf(x4[3].y, wd.y, s);
            s = fmaf(x4[3].z, wd.z, s); s = fmaf(x4[3].w, wd.w, s);
            #pragma unroll
            for (int off = 32; off >= 1; off >>= 1)
                s += __shfl_xor(s, off, 64);
            const float logit = s + b_in[gidx];
            const float act = logit / (1.0f + __expf(-logit));
            #pragma unroll
            for (int k = 0; k < 2; ++k) {
                #pragma unroll
                for (int j = 0; j < 8; ++j) {
                    const int e = k * 512 + lane * 8 + j;
                    acc[k * 8 + j] = fmaf(act, W_out[(size_t)e * WIDTH + gidx], acc[k * 8 + j]);
                }
            }
            node[p] = 2 * node[p] + 1 + ((logit > 0.0f) ? 1 : 0);
        }
    }

    float* orow = out + (size_t)wave * DIM;
    *(float4*)(orow + lane * 8 + 0)       = make_float4(acc[0],  acc[1],  acc[2],  acc[3]);
    *(float4*)(orow + lane * 8 + 4)       = make_float4(acc[4],  acc[5],  acc[6],  acc[7]);
    *(float4*)(orow + 512 + lane * 8 + 0) = make_float4(acc[8],  acc[9],  acc[10], acc[11]);
    *(float4*)(orow + 512 + lane * 8 + 4) = make_float4(acc[12], acc[13], acc[14], acc[15]);
}

extern "C" void kernel_launch(void* const* d_in, const int* in_sizes, int n_in,
                              void* d_out, int out_size, void* d_ws, size_t ws_size,
                              hipStream_t stream) {
    const float* oldx  = (const float*)d_in[0];
    const float* W_in  = (const float*)d_in[1];
    const float* b_in  = (const float*)d_in[2];
    const float* W_out = (const float*)d_in[3];
    float* out = (float*)d_out;

    const int B = in_sizes[0] / DIM;   // 8192 rows

    const size_t half = (size_t)WIDTH * DIM * sizeof(unsigned short);  // 4.18 MB
    const bool use_lp = (ws_size >= 2 * half) && (d_ws != nullptr);

    const int blocks = (B + 3) / 4;    // 4 waves (256 threads) per block

    if (use_lp) {
        unsigned short* WoT = (unsigned short*)d_ws;
        unsigned int*   Wh  = (unsigned int*)((char*)d_ws + half);
        dim3 tg((WIDTH + 63) / 64, DIM / 64);
        transpose_bf16_kernel<<<tg, 256, 0, stream>>>(W_out, WoT);
        const int n4 = WIDTH * DIM / 4;
        convert_f16_kernel<<<(n4 + 255) / 256, 256, 0, stream>>>(W_in, Wh, n4);
        fff_f16_kernel<<<blocks, 256, 0, stream>>>(oldx, W_in, b_in, Wh, WoT, out, B);
    } else {
        fff_fallback_kernel<<<blocks, 256, 0, stream>>>(oldx, W_in, b_in, W_out, out, B);
    }
}